// Round 3
// baseline (1655.699 us; speedup 1.0000x reference)
//
#include <hip/hip_runtime.h>
#include <stdint.h>

#define NNODE 5000
#define NREL  100
#define MAXV  20
#define NH    128
#define NBATCH 32
#define NTOT  100000
#define ETOT  400000
#define AKP   5056   // 79*64: K padded for the alpha GEMM

typedef float  f32x4  __attribute__((ext_vector_type(4)));
typedef __bf16 bf16x8 __attribute__((ext_vector_type(8)));

static __device__ __forceinline__ f32x4 f4zero(){ f32x4 z; z[0]=0.f; z[1]=0.f; z[2]=0.f; z[3]=0.f; return z; }

// ============ generic 128-wide GEMM: D[M x 128] = A[M x 128] @ W[128 x 128]^T (+bias | +=) ============
// A rows < boundary come from A0, else A1 (row - boundary). Same split for D.
// part 0: B = bf16_hi(W), D = acc + bias.  part 1: B = bf16(W - hi), D += acc.
// (hi/lo split on W: weight-rounding error is identical for every row of A, so it
//  does NOT average out in the later mean-pool — must be killed here. A's rounding
//  is uncorrelated across rows and pools away.)
__global__ __launch_bounds__(256) void gemm128(
    const float* __restrict__ A0, const float* __restrict__ A1, int boundary, int M,
    const float* __restrict__ W, const float* __restrict__ bias,
    float* __restrict__ D0, float* __restrict__ D1, int part)
{
  __shared__ __bf16 As[128*128];
  __shared__ __bf16 Bs[128*128];
  const int tid = threadIdx.x, lane = tid & 63, w = tid >> 6;
  const int r0 = blockIdx.x * 128;
  const int arow = tid >> 1, ac0 = (tid & 1) * 64;
  { // stage A (f32 -> bf16)
    const int gr = r0 + arow;
    bf16x8 t8[8];
    if (gr < M){
      const float* src = (gr < boundary) ? (A0 + (size_t)gr * NH) : (A1 + (size_t)(gr - boundary) * NH);
      const f32x4* gp = (const f32x4*)(src + ac0);
      #pragma unroll
      for (int j = 0; j < 16; ++j){
        f32x4 v = gp[j];
        #pragma unroll
        for (int q = 0; q < 4; ++q) t8[j>>1][(j&1)*4+q] = (__bf16)v[q];
      }
    } else {
      #pragma unroll
      for (int j = 0; j < 8; ++j)
        #pragma unroll
        for (int q = 0; q < 8; ++q) t8[j][q] = (__bf16)0.0f;
    }
    #pragma unroll
    for (int j = 0; j < 8; ++j) *(bf16x8*)(&As[arow*128 + ac0 + j*8]) = t8[j];
  }
  { // stage B = hi or lo part of W
    bf16x8 t8[8];
    const f32x4* gp = (const f32x4*)(W + arow*NH + ac0);
    #pragma unroll
    for (int j = 0; j < 16; ++j){
      f32x4 v = gp[j];
      #pragma unroll
      for (int q = 0; q < 4; ++q){
        float f = v[q];
        __bf16 h = (__bf16)f;
        t8[j>>1][(j&1)*4+q] = (part == 0) ? h : (__bf16)(f - (float)h);
      }
    }
    #pragma unroll
    for (int j = 0; j < 8; ++j) *(bf16x8*)(&Bs[arow*128 + ac0 + j*8]) = t8[j];
  }
  __syncthreads();
  const int wr = w >> 1, wc = w & 1;
  f32x4 acc[4][4];
  #pragma unroll
  for (int a = 0; a < 4; ++a)
    #pragma unroll
    for (int b = 0; b < 4; ++b) acc[a][b] = f4zero();
  #pragma unroll
  for (int kk = 0; kk < 4; ++kk){
    const int ko = kk*32 + (lane>>4)*8;
    bf16x8 af[4], bfv[4];
    #pragma unroll
    for (int mi = 0; mi < 4; ++mi) af[mi]  = *(const bf16x8*)(&As[(wr*64 + mi*16 + (lane&15))*128 + ko]);
    #pragma unroll
    for (int nj = 0; nj < 4; ++nj) bfv[nj] = *(const bf16x8*)(&Bs[(wc*64 + nj*16 + (lane&15))*128 + ko]);
    #pragma unroll
    for (int mi = 0; mi < 4; ++mi)
      #pragma unroll
      for (int nj = 0; nj < 4; ++nj)
        acc[mi][nj] = __builtin_amdgcn_mfma_f32_16x16x32_bf16(af[mi], bfv[nj], acc[mi][nj], 0, 0, 0);
  }
  const int rb = r0 + wr*64 + ((lane>>4)*4);
  const int cb = wc*64 + (lane&15);
  #pragma unroll
  for (int mi = 0; mi < 4; ++mi){
    #pragma unroll
    for (int q = 0; q < 4; ++q){
      const int row = rb + mi*16 + q;
      if (row < M){
        #pragma unroll
        for (int nj = 0; nj < 4; ++nj){
          const int col = cb + nj*16;
          float* dp = (row < boundary) ? (D0 + (size_t)row*NH + col) : (D1 + (size_t)(row-boundary)*NH + col);
          float v = acc[mi][nj][q];
          if (part == 0) v += bias[col]; else v += *dp;
          *dp = v;
        }
      }
    }
  }
}

// ============ alpha GEMM: S[640 x 5000] = VN[640 x 5000] @ W[5000 x 5000]^T (bf16 MFMA) ============
// Single-pass bf16 is numerically safe here: VN is exactly 0/1 (bf16-exact), and the
// S-error (~1e-3) is damped by softmax -> *beta -> *x (~0.02) to ~1e-6 in the logits.
__global__ __launch_bounds__(256) void alpha_gemm(
    const float* __restrict__ W, const __bf16* __restrict__ VNb, float* __restrict__ S)
{
  __shared__ __bf16 As[128*64];
  __shared__ __bf16 Bs[128*64];
  const int tid = threadIdx.x, lane = tid & 63, w = tid >> 6;
  const int bid = blockIdx.x;                       // 200 blocks
  const int logical = (bid & 7) * 25 + (bid >> 3);  // XCD-chunked: same m-tile group -> same XCD L2
  const int mt = logical / 5, bt = logical % 5;
  const int wr = w >> 1, wc = w & 1;
  const int brow = tid >> 1, bc0 = (tid & 1) * 32;
  const int gm = mt*128 + brow;
  const bool m_ok = (gm < NNODE);
  const float* wrow = W + (size_t)gm * NNODE;

  f32x4 acc[4][4];
  #pragma unroll
  for (int a = 0; a < 4; ++a)
    #pragma unroll
    for (int b = 0; b < 4; ++b) acc[a][b] = f4zero();

  bf16x8 avr[4];
  f32x4  bvr[8];
  // prologue: load tile 0 into registers
  #pragma unroll
  for (int uu = 0; uu < 4; ++uu){
    int u = tid*4 + uu; int row = u >> 3, cu = (u & 7) * 8;
    avr[uu] = *(const bf16x8*)(VNb + (size_t)(bt*128 + row)*AKP + cu);
  }
  if (m_ok){
    const f32x4* gp = (const f32x4*)(wrow + bc0);
    #pragma unroll
    for (int j = 0; j < 8; ++j) bvr[j] = gp[j];
  } else {
    #pragma unroll
    for (int j = 0; j < 8; ++j) bvr[j] = f4zero();
  }

  for (int kt = 0; kt < 79; ++kt){
    __syncthreads();
    // write staged registers to LDS
    #pragma unroll
    for (int uu = 0; uu < 4; ++uu){
      int u = tid*4 + uu; int row = u >> 3, cu = (u & 7) * 8;
      *(bf16x8*)(&As[row*64 + cu]) = avr[uu];
    }
    {
      bf16x8 t8[4];
      #pragma unroll
      for (int j = 0; j < 8; ++j)
        #pragma unroll
        for (int q = 0; q < 4; ++q) t8[j>>1][(j&1)*4+q] = (__bf16)bvr[j][q];
      #pragma unroll
      for (int j = 0; j < 4; ++j) *(bf16x8*)(&Bs[brow*64 + bc0 + j*8]) = t8[j];
    }
    __syncthreads();
    // prefetch next tile (global latency overlaps MFMA below)
    if (kt < 78){
      const int k0 = (kt+1)*64;
      #pragma unroll
      for (int uu = 0; uu < 4; ++uu){
        int u = tid*4 + uu; int row = u >> 3, cu = (u & 7) * 8;
        avr[uu] = *(const bf16x8*)(VNb + (size_t)(bt*128 + row)*AKP + k0 + cu);
      }
      if (!m_ok){
        #pragma unroll
        for (int j = 0; j < 8; ++j) bvr[j] = f4zero();
      } else if (kt + 1 < 78){
        const f32x4* gp = (const f32x4*)(wrow + k0 + bc0);
        #pragma unroll
        for (int j = 0; j < 8; ++j) bvr[j] = gp[j];
      } else { // tail K-step: guard columns >= 5000
        #pragma unroll
        for (int j = 0; j < 8; ++j){
          f32x4 v;
          #pragma unroll
          for (int q = 0; q < 4; ++q){
            int c = k0 + bc0 + j*4 + q;
            v[q] = (c < NNODE) ? wrow[c] : 0.f;
          }
          bvr[j] = v;
        }
      }
    }
    // MFMA on current LDS tile
    #pragma unroll
    for (int kk = 0; kk < 2; ++kk){
      const int ko = kk*32 + (lane>>4)*8;
      bf16x8 af[4], bfv[4];
      #pragma unroll
      for (int mi = 0; mi < 4; ++mi) af[mi]  = *(const bf16x8*)(&As[(wr*64 + mi*16 + (lane&15))*64 + ko]);
      #pragma unroll
      for (int nj = 0; nj < 4; ++nj) bfv[nj] = *(const bf16x8*)(&Bs[(wc*64 + nj*16 + (lane&15))*64 + ko]);
      #pragma unroll
      for (int mi = 0; mi < 4; ++mi)
        #pragma unroll
        for (int nj = 0; nj < 4; ++nj)
          acc[mi][nj] = __builtin_amdgcn_mfma_f32_16x16x32_bf16(af[mi], bfv[nj], acc[mi][nj], 0, 0, 0);
    }
  }
  const int rb = bt*128 + wr*64 + ((lane>>4)*4);
  const int cbase = mt*128 + wc*64 + (lane&15);
  #pragma unroll
  for (int mi = 0; mi < 4; ++mi)
    #pragma unroll
    for (int nj = 0; nj < 4; ++nj){
      const int col = cbase + nj*16;
      if (col < NNODE){
        #pragma unroll
        for (int q = 0; q < 4; ++q)
          S[(size_t)(rb + mi*16 + q)*NNODE + col] = acc[mi][nj][q];
      }
    }
}

// ============ small prep kernels ============
__global__ __launch_bounds__(256) void vn_kernel(const float* __restrict__ visit, __bf16* __restrict__ VNb){
  int id = blockIdx.x*256 + threadIdx.x;
  if (id >= 640*632) return;
  int r = id / 632, c8 = (id % 632) * 8;
  bf16x8 o;
  #pragma unroll
  for (int j = 0; j < 8; ++j){
    int c = c8 + j;
    float v = (c < NNODE) ? visit[(size_t)r*NNODE + c] : 0.f;
    o[j] = (__bf16)v;
  }
  *(bf16x8*)(VNb + (size_t)r*AKP + c8) = o;
}

__global__ __launch_bounds__(256) void x_init_kernel(const float* __restrict__ nproj, const int* __restrict__ nids, float* __restrict__ x){
  int id = blockIdx.x*256 + threadIdx.x;   // exactly NTOT*128 threads
  int r = id >> 7, f = id & 127;
  x[id] = nproj[(size_t)nids[r]*NH + f];
}

__global__ __launch_bounds__(256) void edge_pre_kernel(const int* __restrict__ esrc, const int* __restrict__ batch, const int* __restrict__ nids, int* __restrict__ eix){
  int e = blockIdx.x*256 + threadIdx.x;
  if (e >= ETOT) return;
  int s = esrc[e];
  eix[e] = batch[s]*NNODE + nids[s];
}

__global__ __launch_bounds__(256) void hist_kernel(const int* __restrict__ edst, int* __restrict__ cnt){
  int e = blockIdx.x*256 + threadIdx.x;
  if (e >= ETOT) return;
  atomicAdd(&cnt[edst[e]], 1);
}

__global__ __launch_bounds__(256) void scan1_kernel(const int* __restrict__ cnt, int* __restrict__ offp, int* __restrict__ bsum){
  __shared__ int sh[256];
  int t = threadIdx.x;
  int base = blockIdx.x*1024 + t*4;
  int v[4]; int ts = 0;
  #pragma unroll
  for (int i = 0; i < 4; ++i){ v[i] = (base+i < NTOT) ? cnt[base+i] : 0; ts += v[i]; }
  sh[t] = ts; __syncthreads();
  for (int o = 1; o < 256; o <<= 1){
    int xv = 0; if (t >= o) xv = sh[t-o];
    __syncthreads();
    if (t >= o) sh[t] += xv;
    __syncthreads();
  }
  int run = sh[t] - ts;
  #pragma unroll
  for (int i = 0; i < 4; ++i){ if (base+i < NTOT) offp[base+i] = run; run += v[i]; }
  if (t == 255) bsum[blockIdx.x] = sh[255];
}

__global__ __launch_bounds__(128) void scan2_kernel(const int* __restrict__ bsum, int* __restrict__ bpre){
  __shared__ int sh[128];
  int t = threadIdx.x;
  int v = (t < 98) ? bsum[t] : 0;
  sh[t] = v; __syncthreads();
  for (int o = 1; o < 128; o <<= 1){
    int xv = 0; if (t >= o) xv = sh[t-o];
    __syncthreads();
    if (t >= o) sh[t] += xv;
    __syncthreads();
  }
  if (t < 98) bpre[t] = sh[t] - v;
}

__global__ __launch_bounds__(256) void scan3_kernel(const int* __restrict__ bpre, int* __restrict__ offp, int* __restrict__ curp){
  int i = blockIdx.x*256 + threadIdx.x;
  if (i >= NTOT) return;
  int v = offp[i] + bpre[i >> 10];
  offp[i] = v; curp[i] = v;
}

__global__ __launch_bounds__(256) void scatter_kernel(const int* __restrict__ edst, int* __restrict__ curp, int* __restrict__ perm){
  int e = blockIdx.x*256 + threadIdx.x;
  if (e >= ETOT) return;
  int p = atomicAdd(&curp[edst[e]], 1);
  perm[p] = e;
}

__global__ __launch_bounds__(256) void beta_kernel(const float* __restrict__ visit, const float* __restrict__ bw, const float* __restrict__ bb, float* __restrict__ beta){
  int wid = blockIdx.x*4 + (threadIdx.x >> 6);
  int lane = threadIdx.x & 63;
  if (wid >= 3*640) return;
  int l = wid / 640, r = wid % 640, vv = r % MAXV;
  const float* vp = visit + (size_t)r*NNODE;
  const float* wp = bw + (size_t)l*NNODE;
  float acc = 0.f;
  for (int n = lane; n < NNODE; n += 64) acc += vp[n]*wp[n];
  #pragma unroll
  for (int o = 32; o > 0; o >>= 1) acc += __shfl_down(acc, o);
  if (lane == 0) beta[wid] = tanhf(acc + bb[l]) * expf(0.01f*(float)(MAXV - vv));
}

__global__ __launch_bounds__(320) void wrel_kernel(const float* __restrict__ relp, const float* __restrict__ wrw, const float* __restrict__ wrb, float* __restrict__ wrel){
  int t = threadIdx.x;
  if (t >= 300) return;
  int l = t / 100, r = t % 100;
  float acc = 0.f;
  for (int h = 0; h < NH; ++h) acc += relp[r*NH + h]*wrw[l*NH + h];
  wrel[t] = acc + wrb[l];
}

__global__ __launch_bounds__(256) void attn_kernel(const float* __restrict__ S, const float* __restrict__ beta_l, float* __restrict__ attn){
  int id = blockIdx.x*256 + threadIdx.x;
  if (id >= NBATCH*NNODE) return;
  int b = id / NNODE;
  const float* sp = S + (size_t)(b*MAXV)*NNODE + (id % NNODE);
  float mx = -1e30f;
  #pragma unroll
  for (int v = 0; v < MAXV; ++v) mx = fmaxf(mx, sp[(size_t)v*NNODE]);
  float den = 0.f, num = 0.f;
  #pragma unroll
  for (int v = 0; v < MAXV; ++v){
    float e = expf(sp[(size_t)v*NNODE] - mx);
    den += e; num += e * beta_l[b*MAXV + v];
  }
  attn[id] = num / den;
}

__global__ __launch_bounds__(256) void agg_kernel(
    const float* __restrict__ x, const float* __restrict__ attn,
    const float* __restrict__ relp, const float* __restrict__ wrel_l,
    const int* __restrict__ eix, const int* __restrict__ esrc, const int* __restrict__ erel,
    const int* __restrict__ offp, const int* __restrict__ cnt, const int* __restrict__ perm,
    float* __restrict__ y)
{
  int node = blockIdx.x*4 + (threadIdx.x >> 6);   // one wave per node
  int lane = threadIdx.x & 63;
  float a1 = x[(size_t)node*NH + lane];           // (1+eps)*x self term, eps=0
  float a2 = x[(size_t)node*NH + 64 + lane];
  int st = offp[node], n = cnt[node];
  for (int t = 0; t < n; ++t){
    int eid = perm[st + t];
    int s  = esrc[eid];
    int rr = erel[eid];
    float at = attn[eix[eid]];
    float wv = wrel_l[rr];
    float x1 = x[(size_t)s*NH + lane];
    float x2 = x[(size_t)s*NH + 64 + lane];
    float r1 = relp[rr*NH + lane];
    float r2 = relp[rr*NH + 64 + lane];
    a1 += fmaxf(x1*at + wv*r1, 0.f);
    a2 += fmaxf(x2*at + wv*r2, 0.f);
  }
  y[(size_t)node*NH + lane] = a1;
  y[(size_t)node*NH + 64 + lane] = a2;
}

__global__ __launch_bounds__(128) void pool_kernel(
    const float* __restrict__ x, const int* __restrict__ batch, const int* __restrict__ nids, const float* __restrict__ ehr,
    float* __restrict__ sum_g, float* __restrict__ sum_n, float* __restrict__ cntb, float* __restrict__ mcntb)
{
  int t = threadIdx.x;
  int r0 = blockIdx.x*128;
  int rend = (r0 + 128 < NTOT) ? r0 + 128 : NTOT;
  float ag = 0.f, an = 0.f, c = 0.f, mc = 0.f; int cur = -1;
  for (int r = r0; r < rend; ++r){
    int b = batch[r];
    if (b != cur){
      if (cur >= 0){
        atomicAdd(&sum_g[cur*NH + t], ag);
        atomicAdd(&sum_n[cur*NH + t], an);
        if (t == 0){ atomicAdd(&cntb[cur], c); atomicAdd(&mcntb[cur], mc); }
      }
      cur = b; ag = an = c = mc = 0.f;
    }
    float xv = x[(size_t)r*NH + t];
    float m = ehr[b*NNODE + nids[r]];
    ag += xv; an += m*xv; c += 1.f; mc += m;
  }
  if (cur >= 0){
    atomicAdd(&sum_g[cur*NH + t], ag);
    atomicAdd(&sum_n[cur*NH + t], an);
    if (t == 0){ atomicAdd(&cntb[cur], c); atomicAdd(&mcntb[cur], mc); }
  }
}

__global__ __launch_bounds__(256) void mlp_kernel(
    const float* __restrict__ sum_g, const float* __restrict__ sum_n, const float* __restrict__ cntb, const float* __restrict__ mcntb,
    const float* __restrict__ w1, const float* __restrict__ b1, const float* __restrict__ w2, const float* __restrict__ b2,
    float* __restrict__ out)
{
  __shared__ float hs[8*256];
  __shared__ float w1s[64*132];
  __shared__ float hid[8*128];
  int t = threadIdx.x;
  int b0 = blockIdx.x * 8;
  for (int e = t; e < 8*256; e += 256){
    int bb = e >> 8, c = e & 255;
    int gb = b0 + bb;
    float v;
    if (c < NH) v = sum_g[gb*NH + c] / fmaxf(cntb[gb], 1.f);
    else        v = sum_n[gb*NH + (c-NH)] / fmaxf(mcntb[gb], 1.f);
    hs[e] = v;
  }
  __syncthreads();
  float acc4[4] = {0.f,0.f,0.f,0.f};
  int j = t & 127, half = t >> 7;
  for (int c = 0; c < 4; ++c){
    for (int e = t; e < 8192; e += 256){
      int jj = e >> 6, kk = e & 63;
      w1s[kk*132 + jj] = w1[jj*256 + c*64 + kk];
    }
    __syncthreads();
    #pragma unroll
    for (int p = 0; p < 4; ++p){
      int bb = p*2 + half;
      float a = 0.f;
      for (int k = 0; k < 64; ++k) a += hs[bb*256 + c*64 + k] * w1s[k*132 + j];
      acc4[p] += a;
    }
    __syncthreads();
  }
  #pragma unroll
  for (int p = 0; p < 4; ++p){
    int bb = p*2 + half;
    hid[bb*128 + j] = fmaxf(acc4[p] + b1[j], 0.f);
  }
  __syncthreads();
  if (t < 8*25){
    int bb = t / 25, o = t % 25;
    float a = b2[o];
    for (int k = 0; k < NH; ++k) a += hid[bb*128 + k] * w2[o*NH + k];
    out[(size_t)(b0 + bb)*25 + o] = a;
  }
}

// ============ host ============
extern "C" void kernel_launch(void* const* d_in, const int* in_sizes, int n_in,
                              void* d_out, int out_size, void* d_ws, size_t ws_size,
                              hipStream_t stream)
{
  const float* node_table = (const float*)d_in[0];
  const float* rel_table  = (const float*)d_in[1];
  const float* lin_w  = (const float*)d_in[2];
  const float* lin_b  = (const float*)d_in[3];
  const float* alpha_w = (const float*)d_in[4];
  // d_in[5] = alpha_b: constant across the softmax (visit) axis -> drops out exactly
  const float* beta_w = (const float*)d_in[6];
  const float* beta_b = (const float*)d_in[7];
  const float* wr_w   = (const float*)d_in[8];
  const float* wr_b   = (const float*)d_in[9];
  const float* conv_w = (const float*)d_in[10];
  const float* conv_b = (const float*)d_in[11];
  const float* mlp_w1 = (const float*)d_in[12];
  const float* mlp_b1 = (const float*)d_in[13];
  const float* mlp_w2 = (const float*)d_in[14];
  const float* mlp_b2 = (const float*)d_in[15];
  const float* visit  = (const float*)d_in[16];
  const float* ehr    = (const float*)d_in[17];
  const int* nids     = (const int*)d_in[18];
  const int* rel_ids  = (const int*)d_in[19];
  const int* eindex   = (const int*)d_in[20];
  const int* batch    = (const int*)d_in[21];
  const int* esrc = eindex;
  const int* edst = eindex + ETOT;

  char* wsb = (char*)d_ws;
  size_t off = 0;
  auto alloc = [&](size_t bytes) -> void* {
    void* p = wsb + off;
    off += (bytes + 255) & ~(size_t)255;
    return p;
  };
  float*  x     = (float*)alloc((size_t)NTOT*NH*4);
  float*  y     = (float*)alloc((size_t)NTOT*NH*4);
  float*  S     = (float*)alloc((size_t)640*NNODE*4);
  __bf16* VNb   = (__bf16*)alloc((size_t)640*AKP*2);
  float*  nproj = (float*)alloc((size_t)NNODE*NH*4);
  float*  rproj = (float*)alloc((size_t)NREL*NH*4);
  float*  attn  = (float*)alloc((size_t)NBATCH*NNODE*4);
  float*  beta  = (float*)alloc(3*640*4);
  float*  wrel  = (float*)alloc(3*100*4);
  int*    eix   = (int*)alloc((size_t)ETOT*4);
  int*    cnt   = (int*)alloc((size_t)NTOT*4);
  int*    offp  = (int*)alloc((size_t)NTOT*4);
  int*    curp  = (int*)alloc((size_t)NTOT*4);
  int*    perm  = (int*)alloc((size_t)ETOT*4);
  int*    bsum  = (int*)alloc(512);
  int*    bpre  = (int*)alloc(512);
  float*  pool  = (float*)alloc((size_t)(NBATCH*NH*2 + 64)*4);
  float*  sum_g = pool;
  float*  sum_n = pool + NBATCH*NH;
  float*  cntb  = pool + NBATCH*NH*2;
  float*  mcntb = cntb + NBATCH;

  hipMemsetAsync(cnt, 0, (size_t)NTOT*4, stream);
  hipMemsetAsync(pool, 0, (size_t)(NBATCH*NH*2 + 64)*4, stream);

  // shared projection (hi + lo weight passes for f32-grade accuracy)
  gemm128<<<40, 256, 0, stream>>>(node_table, rel_table, NNODE, NNODE+NREL, lin_w, lin_b, nproj, rproj, 0);
  gemm128<<<40, 256, 0, stream>>>(node_table, rel_table, NNODE, NNODE+NREL, lin_w, lin_b, nproj, rproj, 1);
  x_init_kernel<<<50000, 256, 0, stream>>>(nproj, nids, x);
  vn_kernel<<<1580, 256, 0, stream>>>(visit, VNb);
  edge_pre_kernel<<<1563, 256, 0, stream>>>(esrc, batch, nids, eix);
  hist_kernel<<<1563, 256, 0, stream>>>(edst, cnt);
  scan1_kernel<<<98, 256, 0, stream>>>(cnt, offp, bsum);
  scan2_kernel<<<1, 128, 0, stream>>>(bsum, bpre);
  scan3_kernel<<<391, 256, 0, stream>>>(bpre, offp, curp);
  scatter_kernel<<<1563, 256, 0, stream>>>(edst, curp, perm);
  beta_kernel<<<480, 256, 0, stream>>>(visit, beta_w, beta_b, beta);
  wrel_kernel<<<1, 320, 0, stream>>>(rproj, wr_w, wr_b, wrel);

  for (int l = 0; l < 3; ++l){
    alpha_gemm<<<200, 256, 0, stream>>>(alpha_w + (size_t)l*NNODE*NNODE, VNb, S);
    attn_kernel<<<625, 256, 0, stream>>>(S, beta + l*640, attn);
    agg_kernel<<<25000, 256, 0, stream>>>(x, attn, rproj, wrel + l*100, eix, esrc, rel_ids, offp, cnt, perm, y);
    gemm128<<<782, 256, 0, stream>>>(y, y, NTOT, NTOT, conv_w + (size_t)l*NH*NH, conv_b + (size_t)l*NH, x, x, 0);
    gemm128<<<782, 256, 0, stream>>>(y, y, NTOT, NTOT, conv_w + (size_t)l*NH*NH, conv_b + (size_t)l*NH, x, x, 1);
  }
  pool_kernel<<<782, 128, 0, stream>>>(x, batch, nids, ehr, sum_g, sum_n, cntb, mcntb);
  mlp_kernel<<<4, 256, 0, stream>>>(sum_g, sum_n, cntb, mcntb, mlp_w1, mlp_b1, mlp_w2, mlp_b2, (float*)d_out);
}

// Round 6
// 1367.355 us; speedup vs baseline: 1.2109x; 1.2109x over previous
//
#include <hip/hip_runtime.h>
#include <stdint.h>

#define NNODE 5000
#define NREL  100
#define MAXV  20
#define NH    128
#define NBATCH 32
#define NTOT  100000
#define ETOT  400000
#define AKP   5056   // 79*64: K padded for the alpha GEMM

typedef float  f32x4  __attribute__((ext_vector_type(4)));
typedef __bf16 bf16x8 __attribute__((ext_vector_type(8)));

static __device__ __forceinline__ f32x4 f4zero(){ f32x4 z; z[0]=0.f; z[1]=0.f; z[2]=0.f; z[3]=0.f; return z; }
// LDS XOR swizzle (T2): spread 8 consecutive rows across 8 distinct 16B slots.
// Applied identically on write and read; bijective within a row (bits 4-6 of byte addr).
static __device__ __forceinline__ int swz(int row, int byte_in_row){ return byte_in_row ^ ((row & 7) << 4); }

// ============ fused 128-wide GEMM: D[M x 128] = A[M x 128] @ W[128 x 128]^T + bias ============
// W is split hi/lo into TWO bf16 LDS tiles; both accumulate into the same f32 acc
// (kills the across-rows-correlated weight-rounding error that mean-pooling can't average).
// A rows < boundary come from A0, else A1 (row - boundary); same split for D.
__global__ __launch_bounds__(256) void gemm128f(
    const float* __restrict__ A0, const float* __restrict__ A1, int boundary, int M,
    const float* __restrict__ W, const float* __restrict__ bias,
    float* __restrict__ D0, float* __restrict__ D1)
{
  __shared__ __bf16 As[64*128];    // 16 KB, swizzled rows (256B stride)
  __shared__ __bf16 Bh[128*128];   // 32 KB
  __shared__ __bf16 Bl[128*128];   // 32 KB
  char* AsB = (char*)As; char* BhB = (char*)Bh; char* BlB = (char*)Bl;
  const int tid = threadIdx.x, lane = tid & 63, w = tid >> 6;
  const int r0 = blockIdx.x * 64;
  { // stage A: row = tid>>2 (0..63), 32 f32 at col (tid&3)*32
    const int row = tid >> 2, c0 = (tid & 3) * 32;
    const int gr = r0 + row;
    bf16x8 t8[4];
    if (gr < M){
      const float* src = (gr < boundary) ? (A0 + (size_t)gr * NH) : (A1 + (size_t)(gr - boundary) * NH);
      const f32x4* gp = (const f32x4*)(src + c0);
      #pragma unroll
      for (int j = 0; j < 8; ++j){
        f32x4 v = gp[j];
        #pragma unroll
        for (int q = 0; q < 4; ++q) t8[j>>1][(j&1)*4+q] = (__bf16)v[q];
      }
    } else {
      #pragma unroll
      for (int j = 0; j < 4; ++j)
        #pragma unroll
        for (int q = 0; q < 8; ++q) t8[j][q] = (__bf16)0.0f;
    }
    #pragma unroll
    for (int j = 0; j < 4; ++j) *(bf16x8*)(AsB + swz(row, row*256 + c0*2 + j*16) ) = t8[j];
  }
  { // stage B hi+lo: row = tid>>1 (0..127), 64 f32 at col (tid&1)*64
    const int row = tid >> 1, c0 = (tid & 1) * 64;
    bf16x8 th[8], tl[8];
    const f32x4* gp = (const f32x4*)(W + row*NH + c0);
    #pragma unroll
    for (int j = 0; j < 16; ++j){
      f32x4 v = gp[j];
      #pragma unroll
      for (int q = 0; q < 4; ++q){
        float f = v[q];
        __bf16 h = (__bf16)f;
        th[j>>1][(j&1)*4+q] = h;
        tl[j>>1][(j&1)*4+q] = (__bf16)(f - (float)h);
      }
    }
    #pragma unroll
    for (int j = 0; j < 8; ++j){
      *(bf16x8*)(BhB + swz(row, row*256 + c0*2 + j*16)) = th[j];
      *(bf16x8*)(BlB + swz(row, row*256 + c0*2 + j*16)) = tl[j];
    }
  }
  __syncthreads();
  // wave w computes A-rows [w*16, w*16+16) x all 128 cols
  f32x4 acc[8];
  #pragma unroll
  for (int n = 0; n < 8; ++n) acc[n] = f4zero();
  #pragma unroll
  for (int kk = 0; kk < 4; ++kk){
    const int kb = kk*64 + (lane>>4)*16;  // byte offset in row (K elements * 2B)
    const int arow = w*16 + (lane&15);
    bf16x8 af = *(const bf16x8*)(AsB + swz(arow, arow*256 + kb));
    #pragma unroll
    for (int nj = 0; nj < 8; ++nj){
      const int brow = nj*16 + (lane&15);
      bf16x8 bh = *(const bf16x8*)(BhB + swz(brow, brow*256 + kb));
      acc[nj] = __builtin_amdgcn_mfma_f32_16x16x32_bf16(af, bh, acc[nj], 0, 0, 0);
      bf16x8 bl = *(const bf16x8*)(BlB + swz(brow, brow*256 + kb));
      acc[nj] = __builtin_amdgcn_mfma_f32_16x16x32_bf16(af, bl, acc[nj], 0, 0, 0);
    }
  }
  const int rb = r0 + w*16 + ((lane>>4)*4);
  #pragma unroll
  for (int q = 0; q < 4; ++q){
    const int row = rb + q;
    if (row < M){
      #pragma unroll
      for (int nj = 0; nj < 8; ++nj){
        const int col = nj*16 + (lane&15);
        float* dp = (row < boundary) ? (D0 + (size_t)row*NH + col) : (D1 + (size_t)(row-boundary)*NH + col);
        *dp = acc[nj][q] + bias[col];
      }
    }
  }
}

// ============ alpha GEMM: S[640 x 5000] = VN[640 x 5000] @ W[5000 x 5000]^T (bf16 MFMA) ============
// 64x64 output tiles -> 790 blocks (occupancy fix). Bijective XCD-chunked swizzle keeps the
// 10 bv-tiles sharing one W m-stripe on the same XCD (W stays L2-resident, HBM-fetch once).
__global__ __launch_bounds__(256) void alpha_gemm(
    const float* __restrict__ W, const __bf16* __restrict__ VNb, float* __restrict__ S)
{
  __shared__ __bf16 As[64*64];   // bv x K tile, 8 KB, swizzled (128B rows)
  __shared__ __bf16 Bs[64*64];   // m  x K tile, 8 KB, swizzled
  char* AsB = (char*)As; char* BsB = (char*)Bs;
  const int tid = threadIdx.x, lane = tid & 63, w = tid >> 6;
  // bijective XCD swizzle over 790 = 6*99 + 2*98 (m204 formula)
  const int bid = blockIdx.x;
  const int xcd = bid & 7, idx = bid >> 3;
  const int logical = (xcd < 6 ? xcd*99 : 6*99 + (xcd-6)*98) + idx;
  const int mt = logical / 10, bt = logical % 10;   // mt 0..78, bt 0..9

  const int srow = tid >> 2, sc = tid & 3;          // staging: row 0..63, quarter sc
  const int gm = mt*64 + srow;
  const bool m_ok = (gm < NNODE);
  const float* wrow = W + (size_t)gm * NNODE;
  const __bf16* vrow = VNb + (size_t)(bt*64 + srow) * AKP;

  f32x4 acc[4];
  #pragma unroll
  for (int n = 0; n < 4; ++n) acc[n] = f4zero();

  bf16x8 avr[2];   // VN prefetch: 16 bf16 at col sc*16
  f32x4  bvr[4];   // W prefetch: 16 f32 at col sc*16
  // prologue: tile kt=0
  #pragma unroll
  for (int h = 0; h < 2; ++h) avr[h] = *(const bf16x8*)(vrow + sc*16 + h*8);
  if (m_ok){
    const f32x4* gp = (const f32x4*)(wrow + sc*16);
    #pragma unroll
    for (int j = 0; j < 4; ++j) bvr[j] = gp[j];
  } else {
    #pragma unroll
    for (int j = 0; j < 4; ++j) bvr[j] = f4zero();
  }

  for (int kt = 0; kt < 79; ++kt){
    __syncthreads();   // previous tile's reads done
    #pragma unroll
    for (int h = 0; h < 2; ++h)
      *(bf16x8*)(AsB + swz(srow, srow*128 + sc*32 + h*16)) = avr[h];
    {
      bf16x8 t8[2];
      #pragma unroll
      for (int j = 0; j < 4; ++j)
        #pragma unroll
        for (int q = 0; q < 4; ++q) t8[j>>1][(j&1)*4+q] = (__bf16)bvr[j][q];
      #pragma unroll
      for (int h = 0; h < 2; ++h)
        *(bf16x8*)(BsB + swz(srow, srow*128 + sc*32 + h*16)) = t8[h];
    }
    __syncthreads();
    // prefetch next K-tile into registers (overlaps MFMA below)
    if (kt < 78){
      const int k0 = (kt+1)*64;
      #pragma unroll
      for (int h = 0; h < 2; ++h) avr[h] = *(const bf16x8*)(vrow + k0 + sc*16 + h*8);
      if (!m_ok){
        #pragma unroll
        for (int j = 0; j < 4; ++j) bvr[j] = f4zero();
      } else if (kt + 1 < 78){
        const f32x4* gp = (const f32x4*)(wrow + k0 + sc*16);
        #pragma unroll
        for (int j = 0; j < 4; ++j) bvr[j] = gp[j];
      } else { // tail K-step: guard cols >= 5000
        #pragma unroll
        for (int j = 0; j < 4; ++j){
          f32x4 v;
          #pragma unroll
          for (int q = 0; q < 4; ++q){
            int c = k0 + sc*16 + j*4 + q;
            v[q] = (c < NNODE) ? wrow[c] : 0.f;
          }
          bvr[j] = v;
        }
      }
    }
    // MFMA: wave w owns bv-rows [w*16, w*16+16) x all 64 m-cols
    #pragma unroll
    for (int kk = 0; kk < 2; ++kk){
      const int kb = kk*64 + (lane>>4)*16;
      const int arow = w*16 + (lane&15);
      bf16x8 af = *(const bf16x8*)(AsB + swz(arow, arow*128 + kb));
      #pragma unroll
      for (int nj = 0; nj < 4; ++nj){
        const int brow = nj*16 + (lane&15);
        bf16x8 bf = *(const bf16x8*)(BsB + swz(brow, brow*128 + kb));
        acc[nj] = __builtin_amdgcn_mfma_f32_16x16x32_bf16(af, bf, acc[nj], 0, 0, 0);
      }
    }
  }
  const int rb = bt*64 + w*16 + ((lane>>4)*4);
  #pragma unroll
  for (int nj = 0; nj < 4; ++nj){
    const int col = mt*64 + nj*16 + (lane&15);
    if (col < NNODE){
      #pragma unroll
      for (int q = 0; q < 4; ++q)
        S[(size_t)(rb + q)*NNODE + col] = acc[nj][q];
    }
  }
}

// ============ small prep kernels ============
__global__ __launch_bounds__(256) void vn_kernel(const float* __restrict__ visit, __bf16* __restrict__ VNb){
  int id = blockIdx.x*256 + threadIdx.x;
  if (id >= 640*632) return;
  int r = id / 632, c8 = (id % 632) * 8;
  bf16x8 o;
  #pragma unroll
  for (int j = 0; j < 8; ++j){
    int c = c8 + j;
    float v = (c < NNODE) ? visit[(size_t)r*NNODE + c] : 0.f;
    o[j] = (__bf16)v;
  }
  *(bf16x8*)(VNb + (size_t)r*AKP + c8) = o;
}

__global__ __launch_bounds__(256) void x_init_kernel(const float* __restrict__ nproj, const int* __restrict__ nids, float* __restrict__ x){
  int id = blockIdx.x*256 + threadIdx.x;   // exactly NTOT*128 threads
  int r = id >> 7, f = id & 127;
  x[id] = nproj[(size_t)nids[r]*NH + f];
}

__global__ __launch_bounds__(256) void edge_pre_kernel(const int* __restrict__ esrc, const int* __restrict__ batch, const int* __restrict__ nids, int* __restrict__ eix){
  int e = blockIdx.x*256 + threadIdx.x;
  if (e >= ETOT) return;
  int s = esrc[e];
  eix[e] = batch[s]*NNODE + nids[s];
}

__global__ __launch_bounds__(256) void hist_kernel(const int* __restrict__ edst, int* __restrict__ cnt){
  int e = blockIdx.x*256 + threadIdx.x;
  if (e >= ETOT) return;
  atomicAdd(&cnt[edst[e]], 1);
}

__global__ __launch_bounds__(256) void scan1_kernel(const int* __restrict__ cnt, int* __restrict__ offp, int* __restrict__ bsum){
  __shared__ int sh[256];
  int t = threadIdx.x;
  int base = blockIdx.x*1024 + t*4;
  int v[4]; int ts = 0;
  #pragma unroll
  for (int i = 0; i < 4; ++i){ v[i] = (base+i < NTOT) ? cnt[base+i] : 0; ts += v[i]; }
  sh[t] = ts; __syncthreads();
  for (int o = 1; o < 256; o <<= 1){
    int xv = 0; if (t >= o) xv = sh[t-o];
    __syncthreads();
    if (t >= o) sh[t] += xv;
    __syncthreads();
  }
  int run = sh[t] - ts;
  #pragma unroll
  for (int i = 0; i < 4; ++i){ if (base+i < NTOT) offp[base+i] = run; run += v[i]; }
  if (t == 255) bsum[blockIdx.x] = sh[255];
}

__global__ __launch_bounds__(128) void scan2_kernel(const int* __restrict__ bsum, int* __restrict__ bpre){
  __shared__ int sh[128];
  int t = threadIdx.x;
  int v = (t < 98) ? bsum[t] : 0;
  sh[t] = v; __syncthreads();
  for (int o = 1; o < 128; o <<= 1){
    int xv = 0; if (t >= o) xv = sh[t-o];
    __syncthreads();
    if (t >= o) sh[t] += xv;
    __syncthreads();
  }
  if (t < 98) bpre[t] = sh[t] - v;
}

__global__ __launch_bounds__(256) void scan3_kernel(const int* __restrict__ bpre, int* __restrict__ offp, int* __restrict__ curp){
  int i = blockIdx.x*256 + threadIdx.x;
  if (i >= NTOT) return;
  int v = offp[i] + bpre[i >> 10];
  offp[i] = v; curp[i] = v;
}

__global__ __launch_bounds__(256) void scatter_kernel(const int* __restrict__ edst, int* __restrict__ curp, int* __restrict__ perm){
  int e = blockIdx.x*256 + threadIdx.x;
  if (e >= ETOT) return;
  int p = atomicAdd(&curp[edst[e]], 1);
  perm[p] = e;
}

__global__ __launch_bounds__(256) void beta_kernel(const float* __restrict__ visit, const float* __restrict__ bw, const float* __restrict__ bb, float* __restrict__ beta){
  int wid = blockIdx.x*4 + (threadIdx.x >> 6);
  int lane = threadIdx.x & 63;
  if (wid >= 3*640) return;
  int l = wid / 640, r = wid % 640, vv = r % MAXV;
  const float* vp = visit + (size_t)r*NNODE;
  const float* wp = bw + (size_t)l*NNODE;
  float acc = 0.f;
  for (int n = lane; n < NNODE; n += 64) acc += vp[n]*wp[n];
  #pragma unroll
  for (int o = 32; o > 0; o >>= 1) acc += __shfl_down(acc, o);
  if (lane == 0) beta[wid] = tanhf(acc + bb[l]) * expf(0.01f*(float)(MAXV - vv));
}

__global__ __launch_bounds__(320) void wrel_kernel(const float* __restrict__ relp, const float* __restrict__ wrw, const float* __restrict__ wrb, float* __restrict__ wrel){
  int t = threadIdx.x;
  if (t >= 300) return;
  int l = t / 100, r = t % 100;
  float acc = 0.f;
  for (int h = 0; h < NH; ++h) acc += relp[r*NH + h]*wrw[l*NH + h];
  wrel[t] = acc + wrb[l];
}

__global__ __launch_bounds__(256) void attn_kernel(const float* __restrict__ S, const float* __restrict__ beta_l, float* __restrict__ attn){
  int id = blockIdx.x*256 + threadIdx.x;
  if (id >= NBATCH*NNODE) return;
  int b = id / NNODE;
  const float* sp = S + (size_t)(b*MAXV)*NNODE + (id % NNODE);
  float mx = -1e30f;
  #pragma unroll
  for (int v = 0; v < MAXV; ++v) mx = fmaxf(mx, sp[(size_t)v*NNODE]);
  float den = 0.f, num = 0.f;
  #pragma unroll
  for (int v = 0; v < MAXV; ++v){
    float e = expf(sp[(size_t)v*NNODE] - mx);
    den += e; num += e * beta_l[b*MAXV + v];
  }
  attn[id] = num / den;
}

__global__ __launch_bounds__(256) void agg_kernel(
    const float* __restrict__ x, const float* __restrict__ attn,
    const float* __restrict__ relp, const float* __restrict__ wrel_l,
    const int* __restrict__ eix, const int* __restrict__ esrc, const int* __restrict__ erel,
    const int* __restrict__ offp, const int* __restrict__ cnt, const int* __restrict__ perm,
    float* __restrict__ y)
{
  int node = blockIdx.x*4 + (threadIdx.x >> 6);   // one wave per node
  int lane = threadIdx.x & 63;
  float a1 = x[(size_t)node*NH + lane];           // (1+eps)*x self term, eps=0
  float a2 = x[(size_t)node*NH + 64 + lane];
  int st = offp[node], n = cnt[node];
  for (int t = 0; t < n; ++t){
    int eid = perm[st + t];
    int s  = esrc[eid];
    int rr = erel[eid];
    float at = attn[eix[eid]];
    float wv = wrel_l[rr];
    float x1 = x[(size_t)s*NH + lane];
    float x2 = x[(size_t)s*NH + 64 + lane];
    float r1 = relp[rr*NH + lane];
    float r2 = relp[rr*NH + 64 + lane];
    a1 += fmaxf(x1*at + wv*r1, 0.f);
    a2 += fmaxf(x2*at + wv*r2, 0.f);
  }
  y[(size_t)node*NH + lane] = a1;
  y[(size_t)node*NH + 64 + lane] = a2;
}

__global__ __launch_bounds__(128) void pool_kernel(
    const float* __restrict__ x, const int* __restrict__ batch, const int* __restrict__ nids, const float* __restrict__ ehr,
    float* __restrict__ sum_g, float* __restrict__ sum_n, float* __restrict__ cntb, float* __restrict__ mcntb)
{
  int t = threadIdx.x;
  int r0 = blockIdx.x*128;
  int rend = (r0 + 128 < NTOT) ? r0 + 128 : NTOT;
  float ag = 0.f, an = 0.f, c = 0.f, mc = 0.f; int cur = -1;
  for (int r = r0; r < rend; ++r){
    int b = batch[r];
    if (b != cur){
      if (cur >= 0){
        atomicAdd(&sum_g[cur*NH + t], ag);
        atomicAdd(&sum_n[cur*NH + t], an);
        if (t == 0){ atomicAdd(&cntb[cur], c); atomicAdd(&mcntb[cur], mc); }
      }
      cur = b; ag = an = c = mc = 0.f;
    }
    float xv = x[(size_t)r*NH + t];
    float m = ehr[b*NNODE + nids[r]];
    ag += xv; an += m*xv; c += 1.f; mc += m;
  }
  if (cur >= 0){
    atomicAdd(&sum_g[cur*NH + t], ag);
    atomicAdd(&sum_n[cur*NH + t], an);
    if (t == 0){ atomicAdd(&cntb[cur], c); atomicAdd(&mcntb[cur], mc); }
  }
}

__global__ __launch_bounds__(256) void mlp_kernel(
    const float* __restrict__ sum_g, const float* __restrict__ sum_n, const float* __restrict__ cntb, const float* __restrict__ mcntb,
    const float* __restrict__ w1, const float* __restrict__ b1, const float* __restrict__ w2, const float* __restrict__ b2,
    float* __restrict__ out)
{
  __shared__ float hs[8*256];
  __shared__ float w1s[64*132];
  __shared__ float hid[8*128];
  int t = threadIdx.x;
  int b0 = blockIdx.x * 8;
  for (int e = t; e < 8*256; e += 256){
    int bb = e >> 8, c = e & 255;
    int gb = b0 + bb;
    float v;
    if (c < NH) v = sum_g[gb*NH + c] / fmaxf(cntb[gb], 1.f);
    else        v = sum_n[gb*NH + (c-NH)] / fmaxf(mcntb[gb], 1.f);
    hs[e] = v;
  }
  __syncthreads();
  float acc4[4] = {0.f,0.f,0.f,0.f};
  int j = t & 127, half = t >> 7;
  for (int c = 0; c < 4; ++c){
    for (int e = t; e < 8192; e += 256){
      int jj = e >> 6, kk = e & 63;
      w1s[kk*132 + jj] = w1[jj*256 + c*64 + kk];
    }
    __syncthreads();
    #pragma unroll
    for (int p = 0; p < 4; ++p){
      int bb = p*2 + half;
      float a = 0.f;
      for (int k = 0; k < 64; ++k) a += hs[bb*256 + c*64 + k] * w1s[k*132 + j];
      acc4[p] += a;
    }
    __syncthreads();
  }
  #pragma unroll
  for (int p = 0; p < 4; ++p){
    int bb = p*2 + half;
    hid[bb*128 + j] = fmaxf(acc4[p] + b1[j], 0.f);
  }
  __syncthreads();
  if (t < 8*25){
    int bb = t / 25, o = t % 25;
    float a = b2[o];
    for (int k = 0; k < NH; ++k) a += hid[bb*128 + k] * w2[o*NH + k];
    out[(size_t)(b0 + bb)*25 + o] = a;
  }
}

// ============ host ============
extern "C" void kernel_launch(void* const* d_in, const int* in_sizes, int n_in,
                              void* d_out, int out_size, void* d_ws, size_t ws_size,
                              hipStream_t stream)
{
  const float* node_table = (const float*)d_in[0];
  const float* rel_table  = (const float*)d_in[1];
  const float* lin_w  = (const float*)d_in[2];
  const float* lin_b  = (const float*)d_in[3];
  const float* alpha_w = (const float*)d_in[4];
  // d_in[5] = alpha_b: constant across the softmax (visit) axis -> drops out exactly
  const float* beta_w = (const float*)d_in[6];
  const float* beta_b = (const float*)d_in[7];
  const float* wr_w   = (const float*)d_in[8];
  const float* wr_b   = (const float*)d_in[9];
  const float* conv_w = (const float*)d_in[10];
  const float* conv_b = (const float*)d_in[11];
  const float* mlp_w1 = (const float*)d_in[12];
  const float* mlp_b1 = (const float*)d_in[13];
  const float* mlp_w2 = (const float*)d_in[14];
  const float* mlp_b2 = (const float*)d_in[15];
  const float* visit  = (const float*)d_in[16];
  const float* ehr    = (const float*)d_in[17];
  const int* nids     = (const int*)d_in[18];
  const int* rel_ids  = (const int*)d_in[19];
  const int* eindex   = (const int*)d_in[20];
  const int* batch    = (const int*)d_in[21];
  const int* esrc = eindex;
  const int* edst = eindex + ETOT;

  char* wsb = (char*)d_ws;
  size_t off = 0;
  auto alloc = [&](size_t bytes) -> void* {
    void* p = wsb + off;
    off += (bytes + 255) & ~(size_t)255;
    return p;
  };
  float*  x     = (float*)alloc((size_t)NTOT*NH*4);
  float*  y     = (float*)alloc((size_t)NTOT*NH*4);
  float*  S     = (float*)alloc((size_t)640*NNODE*4);
  __bf16* VNb   = (__bf16*)alloc((size_t)640*AKP*2);
  float*  nproj = (float*)alloc((size_t)NNODE*NH*4);
  float*  rproj = (float*)alloc((size_t)NREL*NH*4);
  float*  attn  = (float*)alloc((size_t)NBATCH*NNODE*4);
  float*  beta  = (float*)alloc(3*640*4);
  float*  wrel  = (float*)alloc(3*100*4);
  int*    eix   = (int*)alloc((size_t)ETOT*4);
  int*    cnt   = (int*)alloc((size_t)NTOT*4);
  int*    offp  = (int*)alloc((size_t)NTOT*4);
  int*    curp  = (int*)alloc((size_t)NTOT*4);
  int*    perm  = (int*)alloc((size_t)ETOT*4);
  int*    bsum  = (int*)alloc(512);
  int*    bpre  = (int*)alloc(512);
  float*  pool  = (float*)alloc((size_t)(NBATCH*NH*2 + 64)*4);
  float*  sum_g = pool;
  float*  sum_n = pool + NBATCH*NH;
  float*  cntb  = pool + NBATCH*NH*2;
  float*  mcntb = cntb + NBATCH;

  hipMemsetAsync(cnt, 0, (size_t)NTOT*4, stream);
  hipMemsetAsync(pool, 0, (size_t)(NBATCH*NH*2 + 64)*4, stream);

  // shared projection (fused hi+lo weight passes)
  gemm128f<<<80, 256, 0, stream>>>(node_table, rel_table, NNODE, NNODE+NREL, lin_w, lin_b, nproj, rproj);
  x_init_kernel<<<50000, 256, 0, stream>>>(nproj, nids, x);
  vn_kernel<<<1580, 256, 0, stream>>>(visit, VNb);
  edge_pre_kernel<<<1563, 256, 0, stream>>>(esrc, batch, nids, eix);
  hist_kernel<<<1563, 256, 0, stream>>>(edst, cnt);
  scan1_kernel<<<98, 256, 0, stream>>>(cnt, offp, bsum);
  scan2_kernel<<<1, 128, 0, stream>>>(bsum, bpre);
  scan3_kernel<<<391, 256, 0, stream>>>(bpre, offp, curp);
  scatter_kernel<<<1563, 256, 0, stream>>>(edst, curp, perm);
  beta_kernel<<<480, 256, 0, stream>>>(visit, beta_w, beta_b, beta);
  wrel_kernel<<<1, 320, 0, stream>>>(rproj, wr_w, wr_b, wrel);

  for (int l = 0; l < 3; ++l){
    alpha_gemm<<<790, 256, 0, stream>>>(alpha_w + (size_t)l*NNODE*NNODE, VNb, S);
    attn_kernel<<<625, 256, 0, stream>>>(S, beta + l*640, attn);
    agg_kernel<<<25000, 256, 0, stream>>>(x, attn, rproj, wrel + l*100, eix, esrc, rel_ids, offp, cnt, perm, y);
    gemm128f<<<1563, 256, 0, stream>>>(y, y, NTOT, NTOT, conv_w + (size_t)l*NH*NH, conv_b + (size_t)l*NH, x, x);
  }
  pool_kernel<<<782, 128, 0, stream>>>(x, batch, nids, ehr, sum_g, sum_n, cntb, mcntb);
  mlp_kernel<<<4, 256, 0, stream>>>(sum_g, sum_n, cntb, mcntb, mlp_w1, mlp_b1, mlp_w2, mlp_b2, (float*)d_out);
}